// Round 4
// baseline (390.343 us; speedup 1.0000x reference)
//
#include <hip/hip_runtime.h>

#define MDIM 8192
#define NDIM 4096
#define KDIM 4096
#define BM 256
#define BN 256
#define BK 128

typedef int v4i __attribute__((ext_vector_type(4)));
typedef int v16i __attribute__((ext_vector_type(16)));

__device__ __forceinline__ unsigned pack4(int x, int y, int z, int w) {
    return (unsigned)(x & 0xff) | ((unsigned)(y & 0xff) << 8) |
           ((unsigned)(z & 0xff) << 16) | ((unsigned)w << 24);
}

// ---- pass 1: int32 -> packed int8, pre-tiled ---- (unchanged)
// A and B tiles: 256 rows x 128 k, granule-major [kb 0..7][row 0..255],
// granule = 16 B of k for one row == exact MFMA fragment order.
__global__ __launch_bounds__(256) void pack_tiled(const int* __restrict__ x,
                                                  const int* __restrict__ w,
                                                  uint4* __restrict__ xp,
                                                  uint4* __restrict__ wp) {
    __shared__ unsigned lds32[256 * 33];
    const int wg  = blockIdx.x;
    const int tid = threadIdx.x;
    const int kq   = tid & 31;
    const int rsub = tid >> 5;

    const int* src;
    uint4* dst;
    if (wg < 1024) {
        const int mtile = wg >> 5, kiter = wg & 31;
        src = x + (size_t)(mtile * 256) * KDIM + kiter * 128;
        dst = xp + (size_t)(mtile * 32 + kiter) * 2048;
    } else {
        const int ntile = (wg - 1024) >> 5, kiter = wg & 31;
        src = w + (size_t)(ntile * 256) * KDIM + kiter * 128;
        dst = wp + (size_t)(ntile * 32 + kiter) * 2048;
    }
#pragma unroll
    for (int it = 0; it < 32; ++it) {
        const int row = it * 8 + rsub;
        int4 v = *(const int4*)(src + (size_t)row * KDIM + kq * 4);
        lds32[row * 33 + kq] = pack4(v.x, v.y, v.z, v.w);
    }
    __syncthreads();
#pragma unroll
    for (int it = 0; it < 8; ++it) {
        const int g = it * 256 + tid;
        const int kb = g >> 8, row = g & 255;
        const unsigned* p = &lds32[row * 33 + kb * 4];
        uint4 o;
        o.x = p[0]; o.y = p[1]; o.z = p[2]; o.w = p[3];
        dst[g] = o;
    }
}

// ---- pass 2: int8 GEMM, out = x @ W^T ----
// 256x256 tile, 8 waves (2M x 4N), wave tile 128x64, acc[4][2] v16i.
// R4: kill the barrier->read-flood->compute convoy (the invariant 47%-
// MfmaUtil cause across R0-R3). Two changes:
//  (1) ks-granular CROSS-TILE pipeline: clusters (t,ks2),(t,ks3) execute
//      AFTER the barrier at the top of tile t+1, from regs read late in
//      tile t. They are register-only, so they run while the post-barrier
//      fragment reads + B loads of tile t+1 are in flight -- the MFMA pipe
//      never goes empty at a tile boundary.
//  (2) B fragments load global->reg (packed layout IS fragment order;
//      lanes 0-31 read 512 contiguous bytes). B leaves LDS entirely:
//      LDS = A-only 2x32 KB dbuf; LDS reads 128 KB/tile (56 B/cyc demand
//      vs 85 measured ceiling); wave-pairs' duplicate B loads hit L1/L2.
// The only vmcnt(0) is at the tile-top barrier where all outstanding vmem
// (A-DMA of tile t, B-late-half of t-1) is >=1000 cyc old. All other
// waits are compiler-emitted counted lgkm/vmcnt; sched_barrier(0) fences
// pin the read-group / MFMA-cluster interleave.
__global__ __launch_bounds__(512, 2) void gemm_i8_pipe(const char* __restrict__ Ap,
                                                       const char* __restrict__ Bp,
                                                       const _Float16* __restrict__ bias,
                                                       _Float16* __restrict__ out) {
    __shared__ __align__(16) char lds[65536];   // A double buffer only

    const int tid  = threadIdx.x;
    const int lane = tid & 63;
    const int wave = tid >> 6;
    const int wr   = wave >> 2;   // 0..1  (M half)
    const int wcn  = wave & 3;    // 0..3  (N quarter)
    const int l31  = lane & 31;
    const int kg   = lane >> 5;

    // bijective XCD-chunked swizzle: 512 blocks, 8 XCDs, region 4bx x 16by.
    const int lid = blockIdx.y * 16 + blockIdx.x;
    const int xc  = lid & 7, ii = lid >> 3;
    const int bx  = (xc & 3) * 4 + (ii & 3);     // 0..15
    const int by  = (xc >> 2) * 16 + (ii >> 2);  // 0..31
    const int bm0 = by * BM;
    const int bn0 = bx * BN;

    const char* apan = Ap + (size_t)by * (BM * KDIM) + tid * 16;  // DMA src
    const char* bpan = Bp + (size_t)bx * (BN * KDIM);             // B-frag src

    int aoff[4], boffG[2];
#pragma unroll
    for (int mt = 0; mt < 4; ++mt)
        aoff[mt] = (wr * 128 + mt * 32 + l31) * 16 + kg * 4096;
#pragma unroll
    for (int nt = 0; nt < 2; ++nt)
        boffG[nt] = (wcn * 64 + nt * 32 + l31) * 16 + kg * 4096;

    v16i acc[4][2];
#pragma unroll
    for (int mt = 0; mt < 4; ++mt)
#pragma unroll
        for (int nt = 0; nt < 2; ++nt)
#pragma unroll
            for (int i = 0; i < 16; ++i) acc[mt][nt][i] = 0;

    v4i afP[4], afQ[4];        // A-frag ping-pong
    v4i bfE[2][2], bfL[2][2];  // B frags: early (ks0,1) / late (ks2,3)

    auto stageA = [&](int nb) {  // 4 gload_lds/wave: 32 KB A tile of t+1
#pragma unroll
        for (int c2 = 0; c2 < 4; ++c2)
            __builtin_amdgcn_global_load_lds(
                (__attribute__((address_space(1))) const void*)(apan + c2 * 8192),
                (__attribute__((address_space(3))) void*)(lds + nb + c2 * 8192 + tid * 16),
                16, 0, 0);
    };
    auto loadB2 = [&](v4i (&d)[2][2], int ksb) {  // 4 global b128
#pragma unroll
        for (int nt = 0; nt < 2; ++nt)
#pragma unroll
            for (int k = 0; k < 2; ++k)
                d[nt][k] = *(const v4i*)(bpan + boffG[nt] + (ksb + k) * 8192);
    };
    auto readA = [&](v4i (&d)[4], int base, int ks) {  // 4 ds_read_b128
#pragma unroll
        for (int mt = 0; mt < 4; ++mt)
            d[mt] = *(const v4i*)(lds + base + ks * 8192 + aoff[mt]);
    };
    auto cl = [&](const v4i (&a)[4], const v4i (&b)[2][2], int k) {  // 8 MFMA
        __builtin_amdgcn_s_setprio(1);
#pragma unroll
        for (int mt = 0; mt < 4; ++mt)
#pragma unroll
            for (int nt = 0; nt < 2; ++nt)
                acc[mt][nt] = __builtin_amdgcn_mfma_i32_32x32x32_i8(
                    a[mt], b[nt][k], acc[mt][nt], 0, 0, 0);
        __builtin_amdgcn_s_setprio(0);
    };

#define SB0 __builtin_amdgcn_sched_barrier(0)
#define TOPBAR do { asm volatile("s_waitcnt vmcnt(0)" ::: "memory"); \
                    __builtin_amdgcn_s_barrier(); } while (0)

    // ---- prologue: tile 0 ----
    stageA(0);                 // DMA A(0) -> buf0
    TOPBAR; SB0;               // one-time full-latency drain
    loadB2(bfE, 0);            // B(0) ks0,ks1
    stageA(32768);             // DMA A(1) -> buf1
    apan += BM * BK;
    SB0;
    loadB2(bfL, 2);            // B(0) ks2,ks3
    readA(afP, 0, 0);
    readA(afQ, 0, 1);
    SB0;
    cl(afP, bfE, 0);           // (0, ks0)
    SB0;
    readA(afP, 0, 2);
    SB0;
    cl(afQ, bfE, 1);           // (0, ks1)
    SB0;
    readA(afQ, 0, 3);          // held back: (0,ks2),(0,ks3) run after next barrier
    bpan += BN * BK;
    SB0;

    // ---- steady state ----
#pragma unroll 1
    for (int t = 1; t < 32; ++t) {
        const int cur = (t & 1) ? 32768 : 0;
        TOPBAR; SB0;           // confirm buf(t); other slot free (its frags
                               // were consumed into regs before the barrier)
        loadB2(bfE, 0);        // B(t) ks0,ks1 (bfE last read pre-barrier)
        stageA(cur ^ 32768);   // DMA A(t+1) (t=31: lands in wp region, unused)
        apan += BM * BK;
        SB0;
        cl(afP, bfL, 0);       // (t-1, ks2) -- covers B/DMA issue + L2 latency
        SB0;
        readA(afP, cur, 0);
        SB0;
        cl(afQ, bfL, 1);       // (t-1, ks3) -- covers afP ds_reads
        SB0;
        readA(afQ, cur, 1);
        loadB2(bfL, 2);        // B(t) ks2,ks3
        SB0;
        cl(afP, bfE, 0);       // (t, ks0)
        SB0;
        readA(afP, cur, 2);
        SB0;
        cl(afQ, bfE, 1);       // (t, ks1)
        SB0;
        readA(afQ, cur, 3);    // held back for next tile top
        bpan += BN * BK;
        SB0;
    }
    // ---- epilogue clusters: (31, ks2), (31, ks3) ----
    cl(afP, bfL, 0);
    cl(afQ, bfL, 1);

#undef SB0
#undef TOPBAR

    // epilogue: int32 -> fp16 (exact; overflow -> inf matches ref), + bias.
    // C/D layout: col=lane&31, row=(reg&3)+8*(reg>>2)+4*(lane>>5)
    const _Float16 bv0 = bias[bn0 + wcn * 64 + l31];
    const _Float16 bv1 = bias[bn0 + wcn * 64 + 32 + l31];
#pragma unroll
    for (int mt = 0; mt < 4; ++mt) {
#pragma unroll
        for (int nt = 0; nt < 2; ++nt) {
            const int gcol = bn0 + wcn * 64 + nt * 32 + l31;
            const _Float16 bb = nt ? bv1 : bv0;
#pragma unroll
            for (int r = 0; r < 16; ++r) {
                const int rit  = (r & 3) + 8 * (r >> 2) + 4 * kg;
                const int grow = bm0 + wr * 128 + mt * 32 + rit;
                _Float16 h = (_Float16)(float)acc[mt][nt][r] + bb;
                out[(size_t)grow * NDIM + gcol] = h;
            }
        }
    }
}

// ---- fallback (no workspace): non-pipelined, packs in regs ---- (unchanged)
__global__ __launch_bounds__(256, 2) void gemm_i8_fb(const int* __restrict__ A32,
                                                     const int* __restrict__ B32,
                                                     const _Float16* __restrict__ bias,
                                                     _Float16* __restrict__ out) {
    __shared__ char lds[32768];
    const int tid  = threadIdx.x;
    const int lane = tid & 63;
    const int wave = tid >> 6;
    const int bm0 = blockIdx.y * 256;
    const int bn0 = blockIdx.x * 128;
    const int wr  = wave >> 1;
    const int wc  = wave & 1;
    const int l31 = lane & 31;
    const int kg  = lane >> 5;

    int abase[4];
#pragma unroll
    for (int mt = 0; mt < 4; ++mt)
        abase[mt] = kg * 4096 + (wr * 128 + mt * 32 + l31) * 16;

    v16i acc[4][2];
#pragma unroll
    for (int mt = 0; mt < 4; ++mt)
#pragma unroll
        for (int nt = 0; nt < 2; ++nt)
#pragma unroll
            for (int i = 0; i < 16; ++i) acc[mt][nt][i] = 0;

    int aoffs[8];
#pragma unroll
    for (int r = 0; r < 8; ++r) {
        const int c = r * 4 + wave;
        aoffs[r] = (bm0 + (c & 3) * 64 + lane) * KDIM + (c >> 2) * 16;
    }
    for (int k0 = 0; k0 < KDIM; k0 += 128) {
        v4i bfx[2][4];
#pragma unroll
        for (int r = 0; r < 8; ++r) {
            const int c = r * 4 + wave;
            const int4* s = (const int4*)(A32 + (size_t)aoffs[r]);
            int4 v0 = s[0], v1 = s[1], v2 = s[2], v3 = s[3];
            uint4 pk;
            pk.x = pack4(v0.x, v0.y, v0.z, v0.w);
            pk.y = pack4(v1.x, v1.y, v1.z, v1.w);
            pk.z = pack4(v2.x, v2.y, v2.z, v2.w);
            pk.w = pack4(v3.x, v3.y, v3.z, v3.w);
            *(uint4*)(lds + c * 1024 + lane * 16) = pk;
            aoffs[r] += 128;
        }
#pragma unroll
        for (int nt = 0; nt < 2; ++nt)
#pragma unroll
            for (int ks = 0; ks < 4; ++ks) {
                const int* s = B32 + (size_t)(bn0 + wc * 64 + nt * 32 + l31) * KDIM
                               + k0 + (2 * ks + kg) * 16;
                int4 v0 = ((const int4*)s)[0], v1 = ((const int4*)s)[1];
                int4 v2 = ((const int4*)s)[2], v3 = ((const int4*)s)[3];
                bfx[nt][ks][0] = (int)pack4(v0.x, v0.y, v0.z, v0.w);
                bfx[nt][ks][1] = (int)pack4(v1.x, v1.y, v1.z, v1.w);
                bfx[nt][ks][2] = (int)pack4(v2.x, v2.y, v2.z, v2.w);
                bfx[nt][ks][3] = (int)pack4(v3.x, v3.y, v3.z, v3.w);
            }
        __syncthreads();
#pragma unroll
        for (int ks = 0; ks < 4; ++ks) {
            v4i afr[4];
#pragma unroll
            for (int mt = 0; mt < 4; ++mt)
                afr[mt] = *(const v4i*)(lds + abase[mt] + ks * 8192);
#pragma unroll
            for (int mt = 0; mt < 4; ++mt)
#pragma unroll
                for (int nt = 0; nt < 2; ++nt)
                    acc[mt][nt] = __builtin_amdgcn_mfma_i32_32x32x32_i8(
                        afr[mt], bfx[nt][ks], acc[mt][nt], 0, 0, 0);
        }
        __syncthreads();
    }

    const _Float16 bv0 = bias[bn0 + wc * 64 + l31];
    const _Float16 bv1 = bias[bn0 + wc * 64 + 32 + l31];
#pragma unroll
    for (int mt = 0; mt < 4; ++mt) {
#pragma unroll
        for (int nt = 0; nt < 2; ++nt) {
            const int gcol = bn0 + wc * 64 + nt * 32 + l31;
            const _Float16 bb = nt ? bv1 : bv0;
#pragma unroll
            for (int r = 0; r < 16; ++r) {
                const int rit  = (r & 3) + 8 * (r >> 2) + 4 * kg;
                const int grow = bm0 + wr * 128 + mt * 32 + rit;
                _Float16 h = (_Float16)(float)acc[mt][nt][r] + bb;
                out[(size_t)grow * NDIM + gcol] = h;
            }
        }
    }
}

extern "C" void kernel_launch(void* const* d_in, const int* in_sizes, int n_in,
                              void* d_out, int out_size, void* d_ws, size_t ws_size,
                              hipStream_t stream) {
    const int* x = (const int*)d_in[0];
    const int* w = (const int*)d_in[1];
    const _Float16* bias = (const _Float16*)d_in[2];
    _Float16* out = (_Float16*)d_out;

    const size_t xbytes = (size_t)MDIM * KDIM;  // packed int8 bytes
    const size_t wbytes = (size_t)NDIM * KDIM;

    if (ws_size >= xbytes + wbytes) {
        char* xp = (char*)d_ws;
        char* wp = xp + xbytes;
        pack_tiled<<<1536, 256, 0, stream>>>(x, w, (uint4*)xp, (uint4*)wp);
        gemm_i8_pipe<<<dim3(NDIM / BN, MDIM / BM), 512, 0, stream>>>(
            (const char*)xp, (const char*)wp, bias, out);
    } else {
        gemm_i8_fb<<<dim3(NDIM / 128, MDIM / 256), 256, 0, stream>>>(
            x, w, bias, out);
    }
}

// Round 5
// 377.494 us; speedup vs baseline: 1.0340x; 1.0340x over previous
//
#include <hip/hip_runtime.h>

#define MDIM 8192
#define NDIM 4096
#define KDIM 4096
#define BM 256
#define BN 256
#define BK 128

typedef int v4i __attribute__((ext_vector_type(4)));
typedef int v16i __attribute__((ext_vector_type(16)));

__device__ __forceinline__ unsigned pack4(int x, int y, int z, int w) {
    return (unsigned)(x & 0xff) | ((unsigned)(y & 0xff) << 8) |
           ((unsigned)(z & 0xff) << 16) | ((unsigned)w << 24);
}

// ---- pass 1: int32 -> packed int8, pre-tiled ---- (unchanged)
// A and B tiles: 256 rows x 128 k, granule-major [kb 0..7][row 0..255],
// granule = 16 B of k for one row == exact MFMA fragment order.
__global__ __launch_bounds__(256) void pack_tiled(const int* __restrict__ x,
                                                  const int* __restrict__ w,
                                                  uint4* __restrict__ xp,
                                                  uint4* __restrict__ wp) {
    __shared__ unsigned lds32[256 * 33];
    const int wg  = blockIdx.x;
    const int tid = threadIdx.x;
    const int kq   = tid & 31;
    const int rsub = tid >> 5;

    const int* src;
    uint4* dst;
    if (wg < 1024) {
        const int mtile = wg >> 5, kiter = wg & 31;
        src = x + (size_t)(mtile * 256) * KDIM + kiter * 128;
        dst = xp + (size_t)(mtile * 32 + kiter) * 2048;
    } else {
        const int ntile = (wg - 1024) >> 5, kiter = wg & 31;
        src = w + (size_t)(ntile * 256) * KDIM + kiter * 128;
        dst = wp + (size_t)(ntile * 32 + kiter) * 2048;
    }
#pragma unroll
    for (int it = 0; it < 32; ++it) {
        const int row = it * 8 + rsub;
        int4 v = *(const int4*)(src + (size_t)row * KDIM + kq * 4);
        lds32[row * 33 + kq] = pack4(v.x, v.y, v.z, v.w);
    }
    __syncthreads();
#pragma unroll
    for (int it = 0; it < 8; ++it) {
        const int g = it * 256 + tid;
        const int kb = g >> 8, row = g & 255;
        const unsigned* p = &lds32[row * 33 + kb * 4];
        uint4 o;
        o.x = p[0]; o.y = p[1]; o.z = p[2]; o.w = p[3];
        dst[g] = o;
    }
}

// ---- pass 2: int8 GEMM, out = x @ W^T ----
// 256x256 tile, 8 waves (2M x 4N), wave tile 128x64, acc[4][2] v16i.
// LDS 128 KB double buffer (A 32 KB + B 32 KB per buf), both DMA-staged.
// R5 = R3 (best, 133 us) + cross-tile holdback (the R4 idea, minus the
// B-from-global mistake that caused R4's regression):
//   clusters (t,ks2),(t,ks3) run AFTER the TOPBAR of tile t+1, from
//   afP/afQ/bfL regs read late in tile t. R3's measured per-tile time
//   (4990 cyc) == MFMA(2340) + LDS reads(2260) + DMA(~400) fully
//   SERIALIZED: at 2 waves/SIMD the post-barrier read-flood has no MFMA
//   work to hide under. The held clusters are register-only -> they
//   execute while tile t+1's bfE/afP ds_reads are in flight, and the
//   stage-DMA issue moves off the barrier into the covered region.
// Only vmcnt(0) is at the tile-top barrier, draining stage(t) issued
// mid-tile t-1 (~3000 cyc coverage). B stays in LDS (R4 lesson).
__global__ __launch_bounds__(512, 2) void gemm_i8_hold(const char* __restrict__ Ap,
                                                       const char* __restrict__ Bp,
                                                       const _Float16* __restrict__ bias,
                                                       _Float16* __restrict__ out) {
    __shared__ __align__(16) char lds[131072];

    const int tid  = threadIdx.x;
    const int lane = tid & 63;
    const int wave = tid >> 6;
    const int wr   = wave >> 2;   // 0..1  (M half)
    const int wcn  = wave & 3;    // 0..3  (N quarter)
    const int l31  = lane & 31;
    const int kg   = lane >> 5;

    // bijective XCD-chunked swizzle: 512 blocks, 8 XCDs, region 4bx x 16by.
    const int lid = blockIdx.y * 16 + blockIdx.x;
    const int xc  = lid & 7, ii = lid >> 3;
    const int bx  = (xc & 3) * 4 + (ii & 3);     // 0..15
    const int by  = (xc >> 2) * 16 + (ii >> 2);  // 0..31
    const int bm0 = by * BM;
    const int bn0 = bx * BN;

    const char* apan = Ap + (size_t)by * (BM * KDIM) + tid * 16;
    const char* bpan = Bp + (size_t)bx * (BN * KDIM) + tid * 16;

    int aoff[4], boff[2];
#pragma unroll
    for (int mt = 0; mt < 4; ++mt)
        aoff[mt] = (wr * 128 + mt * 32 + l31) * 16 + kg * 4096;
#pragma unroll
    for (int nt = 0; nt < 2; ++nt)
        boff[nt] = (wcn * 64 + nt * 32 + l31) * 16 + kg * 4096;

    v16i acc[4][2];
#pragma unroll
    for (int mt = 0; mt < 4; ++mt)
#pragma unroll
        for (int nt = 0; nt < 2; ++nt)
#pragma unroll
            for (int i = 0; i < 16; ++i) acc[mt][nt][i] = 0;

    v4i afP[4], afQ[4];        // A-frag ping-pong (persist across barrier)
    v4i bfE[2][2], bfL[2][2];  // B frags early (ks0,1) / late (ks2,3)

    auto stageA = [&](int nb) {  // 4 gload_lds: 32 KB A tile
#pragma unroll
        for (int c2 = 0; c2 < 4; ++c2)
            __builtin_amdgcn_global_load_lds(
                (__attribute__((address_space(1))) const void*)(apan + c2 * 8192),
                (__attribute__((address_space(3))) void*)(lds + nb + c2 * 8192 + tid * 16),
                16, 0, 0);
    };
    auto stageB = [&](int nb) {  // 4 gload_lds: 32 KB B tile
#pragma unroll
        for (int c2 = 0; c2 < 4; ++c2)
            __builtin_amdgcn_global_load_lds(
                (__attribute__((address_space(1))) const void*)(bpan + c2 * 8192),
                (__attribute__((address_space(3))) void*)(lds + nb + 32768 + c2 * 8192 + tid * 16),
                16, 0, 0);
    };
    auto readA = [&](v4i (&d)[4], int base, int ks) {  // 4 ds_read_b128
#pragma unroll
        for (int mt = 0; mt < 4; ++mt)
            d[mt] = *(const v4i*)(lds + base + ks * 8192 + aoff[mt]);
    };
    auto readB2 = [&](v4i (&d)[2][2], int base, int ksb) {  // 4 ds_read_b128
#pragma unroll
        for (int nt = 0; nt < 2; ++nt)
#pragma unroll
            for (int k = 0; k < 2; ++k)
                d[nt][k] = *(const v4i*)(lds + base + 32768 + (ksb + k) * 8192 + boff[nt]);
    };
    auto cl = [&](const v4i (&a)[4], const v4i (&b)[2][2], int k) {  // 8 MFMA
        __builtin_amdgcn_s_setprio(1);
#pragma unroll
        for (int mt = 0; mt < 4; ++mt)
#pragma unroll
            for (int nt = 0; nt < 2; ++nt)
                acc[mt][nt] = __builtin_amdgcn_mfma_i32_32x32x32_i8(
                    a[mt], b[nt][k], acc[mt][nt], 0, 0, 0);
        __builtin_amdgcn_s_setprio(0);
    };

#define SB0 __builtin_amdgcn_sched_barrier(0)
#define TOPBAR do { asm volatile("s_waitcnt vmcnt(0)" ::: "memory"); \
                    __builtin_amdgcn_s_barrier(); } while (0)

    // ---- prologue: tile 0 ----
    stageA(0); stageB(0);               // tile 0 -> buf0
    apan += BM * BK; bpan += BN * BK;
    TOPBAR; SB0;                        // one-time full-latency drain
    readB2(bfE, 0, 0);                  // B(0) ks0,ks1
    readA(afP, 0, 0);
    SB0;
    stageA(65536); stageB(65536);       // tile 1 -> buf1
    apan += BM * BK; bpan += BN * BK;
    SB0;
    readA(afQ, 0, 1);
    readB2(bfL, 0, 2);                  // B(0) ks2,ks3
    SB0;
    cl(afP, bfE, 0);                    // (0, ks0)
    SB0;
    readA(afP, 0, 2);
    SB0;
    cl(afQ, bfE, 1);                    // (0, ks1)
    SB0;
    readA(afQ, 0, 3);                   // (0,ks2),(0,ks3) held to next tile
    SB0;

    // ---- steady state: tile t computed, (t-1) tail executed post-barrier ----
#pragma unroll 1
    for (int t = 1; t < 32; ++t) {
        const int cur = (t & 1) ? 65536 : 0;
        TOPBAR; SB0;                    // drains stage(t), issued mid-tile t-1
        readB2(bfE, cur, 0);            // B(t) ks0,ks1     (LDS reads...)
        SB0;
        cl(afP, bfL, 0);                // (t-1, ks2)  -- reg-only, covers them
        SB0;
        readA(afP, cur, 0);             // A(t) ks0
        SB0;
        cl(afQ, bfL, 1);                // (t-1, ks3)  -- covers afP reads
        SB0;
        if (t < 31) {                   // stage tile t+1 (off the barrier,
            stageA(cur ^ 65536);        //  under the covered region)
            stageB(cur ^ 65536);
            apan += BM * BK; bpan += BN * BK;
        }
        readA(afQ, cur, 1);             // A(t) ks1
        readB2(bfL, cur, 2);            // B(t) ks2,ks3
        SB0;
        cl(afP, bfE, 0);                // (t, ks0)
        SB0;
        readA(afP, cur, 2);             // A(t) ks2
        SB0;
        cl(afQ, bfE, 1);                // (t, ks1)
        SB0;
        readA(afQ, cur, 3);             // A(t) ks3; held with bfL to t+1
        SB0;
    }
    // ---- epilogue clusters: (31, ks2), (31, ks3) ----
    cl(afP, bfL, 0);
    cl(afQ, bfL, 1);

#undef SB0
#undef TOPBAR

    // epilogue: int32 -> fp16 (exact; overflow -> inf matches ref), + bias.
    // C/D layout: col=lane&31, row=(reg&3)+8*(reg>>2)+4*(lane>>5)
    const _Float16 bv0 = bias[bn0 + wcn * 64 + l31];
    const _Float16 bv1 = bias[bn0 + wcn * 64 + 32 + l31];
#pragma unroll
    for (int mt = 0; mt < 4; ++mt) {
#pragma unroll
        for (int nt = 0; nt < 2; ++nt) {
            const int gcol = bn0 + wcn * 64 + nt * 32 + l31;
            const _Float16 bb = nt ? bv1 : bv0;
#pragma unroll
            for (int r = 0; r < 16; ++r) {
                const int rit  = (r & 3) + 8 * (r >> 2) + 4 * kg;
                const int grow = bm0 + wr * 128 + mt * 32 + rit;
                _Float16 h = (_Float16)(float)acc[mt][nt][r] + bb;
                out[(size_t)grow * NDIM + gcol] = h;
            }
        }
    }
}

// ---- fallback (no workspace): non-pipelined, packs in regs ---- (unchanged)
__global__ __launch_bounds__(256, 2) void gemm_i8_fb(const int* __restrict__ A32,
                                                     const int* __restrict__ B32,
                                                     const _Float16* __restrict__ bias,
                                                     _Float16* __restrict__ out) {
    __shared__ char lds[32768];
    const int tid  = threadIdx.x;
    const int lane = tid & 63;
    const int wave = tid >> 6;
    const int bm0 = blockIdx.y * 256;
    const int bn0 = blockIdx.x * 128;
    const int wr  = wave >> 1;
    const int wc  = wave & 1;
    const int l31 = lane & 31;
    const int kg  = lane >> 5;

    int abase[4];
#pragma unroll
    for (int mt = 0; mt < 4; ++mt)
        abase[mt] = kg * 4096 + (wr * 128 + mt * 32 + l31) * 16;

    v16i acc[4][2];
#pragma unroll
    for (int mt = 0; mt < 4; ++mt)
#pragma unroll
        for (int nt = 0; nt < 2; ++nt)
#pragma unroll
            for (int i = 0; i < 16; ++i) acc[mt][nt][i] = 0;

    int aoffs[8];
#pragma unroll
    for (int r = 0; r < 8; ++r) {
        const int c = r * 4 + wave;
        aoffs[r] = (bm0 + (c & 3) * 64 + lane) * KDIM + (c >> 2) * 16;
    }
    for (int k0 = 0; k0 < KDIM; k0 += 128) {
        v4i bfx[2][4];
#pragma unroll
        for (int r = 0; r < 8; ++r) {
            const int c = r * 4 + wave;
            const int4* s = (const int4*)(A32 + (size_t)aoffs[r]);
            int4 v0 = s[0], v1 = s[1], v2 = s[2], v3 = s[3];
            uint4 pk;
            pk.x = pack4(v0.x, v0.y, v0.z, v0.w);
            pk.y = pack4(v1.x, v1.y, v1.z, v1.w);
            pk.z = pack4(v2.x, v2.y, v2.z, v2.w);
            pk.w = pack4(v3.x, v3.y, v3.z, v3.w);
            *(uint4*)(lds + c * 1024 + lane * 16) = pk;
            aoffs[r] += 128;
        }
#pragma unroll
        for (int nt = 0; nt < 2; ++nt)
#pragma unroll
            for (int ks = 0; ks < 4; ++ks) {
                const int* s = B32 + (size_t)(bn0 + wc * 64 + nt * 32 + l31) * KDIM
                               + k0 + (2 * ks + kg) * 16;
                int4 v0 = ((const int4*)s)[0], v1 = ((const int4*)s)[1];
                int4 v2 = ((const int4*)s)[2], v3 = ((const int4*)s)[3];
                bfx[nt][ks][0] = (int)pack4(v0.x, v0.y, v0.z, v0.w);
                bfx[nt][ks][1] = (int)pack4(v1.x, v1.y, v1.z, v1.w);
                bfx[nt][ks][2] = (int)pack4(v2.x, v2.y, v2.z, v2.w);
                bfx[nt][ks][3] = (int)pack4(v3.x, v3.y, v3.z, v3.w);
            }
        __syncthreads();
#pragma unroll
        for (int ks = 0; ks < 4; ++ks) {
            v4i afr[4];
#pragma unroll
            for (int mt = 0; mt < 4; ++mt)
                afr[mt] = *(const v4i*)(lds + abase[mt] + ks * 8192);
#pragma unroll
            for (int mt = 0; mt < 4; ++mt)
#pragma unroll
                for (int nt = 0; nt < 2; ++nt)
                    acc[mt][nt] = __builtin_amdgcn_mfma_i32_32x32x32_i8(
                        afr[mt], bfx[nt][ks], acc[mt][nt], 0, 0, 0);
        }
        __syncthreads();
    }

    const _Float16 bv0 = bias[bn0 + wc * 64 + l31];
    const _Float16 bv1 = bias[bn0 + wc * 64 + 32 + l31];
#pragma unroll
    for (int mt = 0; mt < 4; ++mt) {
#pragma unroll
        for (int nt = 0; nt < 2; ++nt) {
            const int gcol = bn0 + wc * 64 + nt * 32 + l31;
            const _Float16 bb = nt ? bv1 : bv0;
#pragma unroll
            for (int r = 0; r < 16; ++r) {
                const int rit  = (r & 3) + 8 * (r >> 2) + 4 * kg;
                const int grow = bm0 + wr * 128 + mt * 32 + rit;
                _Float16 h = (_Float16)(float)acc[mt][nt][r] + bb;
                out[(size_t)grow * NDIM + gcol] = h;
            }
        }
    }
}

extern "C" void kernel_launch(void* const* d_in, const int* in_sizes, int n_in,
                              void* d_out, int out_size, void* d_ws, size_t ws_size,
                              hipStream_t stream) {
    const int* x = (const int*)d_in[0];
    const int* w = (const int*)d_in[1];
    const _Float16* bias = (const _Float16*)d_in[2];
    _Float16* out = (_Float16*)d_out;

    const size_t xbytes = (size_t)MDIM * KDIM;  // packed int8 bytes
    const size_t wbytes = (size_t)NDIM * KDIM;

    if (ws_size >= xbytes + wbytes) {
        char* xp = (char*)d_ws;
        char* wp = xp + xbytes;
        pack_tiled<<<1536, 256, 0, stream>>>(x, w, (uint4*)xp, (uint4*)wp);
        gemm_i8_hold<<<dim3(NDIM / BN, MDIM / BM), 512, 0, stream>>>(
            (const char*)xp, (const char*)wp, bias, out);
    } else {
        gemm_i8_fb<<<dim3(NDIM / 128, MDIM / 256), 256, 0, stream>>>(
            x, w, bias, out);
    }
}